// Round 5
// baseline (1020.615 us; speedup 1.0000x reference)
//
#include <hip/hip_runtime.h>
#include <hip/hip_fp16.h>

#define N_NODES 50000
#define N_EDGES 800000
#define NGRAPH  256
#define FDIM    64
#define EDIM    16

__device__ __forceinline__ int rfl(int v) { return __builtin_amdgcn_readfirstlane(v); }

// ---------------- small setup kernels ----------------

__global__ void k_init_out(float* __restrict__ out, const float* __restrict__ b_out) {
    int g = blockIdx.x * blockDim.x + threadIdx.x;
    if (g < NGRAPH) out[g] = b_out[0];
}

__global__ void k_count(const int* __restrict__ dst, int* __restrict__ cnt) {
    int e = blockIdx.x * blockDim.x + threadIdx.x;
    if (e < N_EDGES) atomicAdd(&cnt[dst[e]], 1);
}

__global__ void k_cvt_x(const float* __restrict__ x, __half* __restrict__ x16) {
    int t = blockIdx.x * blockDim.x + threadIdx.x;
    if (t < N_NODES * FDIM) x16[t] = __float2half(x[t]);
}

// single-block exclusive scan of cnt -> rowp (N+1), also init cursor
__global__ void k_scan(const int* __restrict__ cnt, int* __restrict__ rowp,
                       int* __restrict__ cur) {
    __shared__ int part[1024];
    int t = threadIdx.x;
    const int CH = (N_NODES + 1023) / 1024;
    int s = 0;
    int start = t * CH;
    for (int i = 0; i < CH; i++) {
        int idx = start + i;
        if (idx < N_NODES) s += cnt[idx];
    }
    part[t] = s;
    __syncthreads();
    for (int off = 1; off < 1024; off <<= 1) {
        int v = (t >= off) ? part[t - off] : 0;
        __syncthreads();
        part[t] += v;
        __syncthreads();
    }
    int run = (t == 0) ? 0 : part[t - 1];
    for (int i = 0; i < CH; i++) {
        int idx = start + i;
        if (idx < N_NODES) {
            rowp[idx] = run;
            cur[idx]  = run;
            run += cnt[idx];
        }
    }
    if (t == 1023) rowp[N_NODES] = part[1023];
}

// fill CSR col + edge permutation (eperm[pos] = original edge id)
__global__ void k_fill(const int* __restrict__ src, const int* __restrict__ dst,
                       int* __restrict__ cur, int* __restrict__ col,
                       int* __restrict__ eperm) {
    int e = blockIdx.x * blockDim.x + threadIdx.x;
    if (e < N_EDGES) {
        int pos = atomicAdd(&cur[dst[e]], 1);
        col[pos] = src[e];
        eperm[pos] = e;
    }
}

// ea[i][0:16] = sum of edge_attr rows of in-edges of i (no self row; handled
// via csum in k_h0base). 16 edges per load instruction (float4/lane, 4 lanes/row).
__global__ __launch_bounds__(256, 8) void k_ea_agg(
    const float* __restrict__ edge_attr,
    const int* __restrict__ rowp, const int* __restrict__ eperm,
    float* __restrict__ ea) {
    int lane = threadIdx.x & 63, wid = threadIdx.x >> 6;
    int q2 = lane >> 2, c2 = lane & 3;
    const float4* a4 = (const float4*)edge_attr;  // row = 4 float4
    int gw = blockIdx.x * 4 + wid, nw = gridDim.x * 4;
    for (int i = gw; i < N_NODES; i += nw) {
        int beg = rfl(rowp[i]);
        int end = rfl(rowp[i + 1]);
        float x0 = 0.f, x1 = 0.f, x2 = 0.f, x3 = 0.f;
        int p = beg;
        for (; p + 16 <= end; p += 16) {
            int e = eperm[p + q2];
            float4 v = a4[e * 4 + c2];
            x0 += v.x; x1 += v.y; x2 += v.z; x3 += v.w;
        }
        if (p + q2 < end) {
            int e = eperm[p + q2];
            float4 v = a4[e * 4 + c2];
            x0 += v.x; x1 += v.y; x2 += v.z; x3 += v.w;
        }
#pragma unroll
        for (int m = 4; m <= 32; m <<= 1) {
            x0 += __shfl_xor(x0, m, 64);
            x1 += __shfl_xor(x1, m, 64);
            x2 += __shfl_xor(x2, m, 64);
            x3 += __shfl_xor(x3, m, 64);
        }
        if (lane < 4) ((float4*)ea)[i * 4 + c2] = make_float4(x0, x1, x2, x3);
    }
}

// ---------------- pure gather: agg[i] = sum_{j in-neighbors} h16[j] ---------
// quarter-wave per row: 4 edges per load instruction (uint2 = 4 halves/lane),
// 32 edges (8 loads) in flight. Named scalars only (no promote-alloca).
#define LOAD4(JA, JB, JC, JD)                                               \
    {                                                                       \
        int jj = (q == 0) ? (JA) : ((q == 1) ? (JB) : ((q == 2) ? (JC) : (JD))); \
        uint2 v = h4[(size_t)jj * 16 + c];                                  \
        float2 lo = __half22float2(__builtin_bit_cast(__half2, v.x));       \
        float2 hi = __half22float2(__builtin_bit_cast(__half2, v.y));       \
        a0 += lo.x; a1 += lo.y; a2 += hi.x; a3 += hi.y;                     \
    }

__global__ __launch_bounds__(256, 8) void k_gather(
    const __half* __restrict__ h16,
    const int* __restrict__ rowp, const int* __restrict__ col,
    float* __restrict__ agg) {
    int lane = threadIdx.x & 63, wid = threadIdx.x >> 6;
    int q = lane >> 4;   // which of 4 rows
    int c = lane & 15;   // uint2 slot within 128B row
    const uint2* h4 = (const uint2*)h16;
    int gw = blockIdx.x * 4 + wid, nw = gridDim.x * 4;
    for (int i = gw; i < N_NODES; i += nw) {
        int beg = rfl(rowp[i]);
        int end = rfl(rowp[i + 1]);
        float a0 = 0.f, a1 = 0.f, a2 = 0.f, a3 = 0.f;
        int p = beg;
        for (; p + 32 <= end; p += 32) {
            int j0  = col[p + 0],  j1  = col[p + 1],  j2  = col[p + 2],  j3  = col[p + 3];
            int j4  = col[p + 4],  j5  = col[p + 5],  j6  = col[p + 6],  j7  = col[p + 7];
            int j8  = col[p + 8],  j9  = col[p + 9],  j10 = col[p + 10], j11 = col[p + 11];
            int j12 = col[p + 12], j13 = col[p + 13], j14 = col[p + 14], j15 = col[p + 15];
            int j16 = col[p + 16], j17 = col[p + 17], j18 = col[p + 18], j19 = col[p + 19];
            int j20 = col[p + 20], j21 = col[p + 21], j22 = col[p + 22], j23 = col[p + 23];
            int j24 = col[p + 24], j25 = col[p + 25], j26 = col[p + 26], j27 = col[p + 27];
            int j28 = col[p + 28], j29 = col[p + 29], j30 = col[p + 30], j31 = col[p + 31];
            LOAD4(j0,  j1,  j2,  j3)  LOAD4(j4,  j5,  j6,  j7)
            LOAD4(j8,  j9,  j10, j11) LOAD4(j12, j13, j14, j15)
            LOAD4(j16, j17, j18, j19) LOAD4(j20, j21, j22, j23)
            LOAD4(j24, j25, j26, j27) LOAD4(j28, j29, j30, j31)
        }
        for (; p + 4 <= end; p += 4) {
            int jA = col[p], jB = col[p + 1], jC = col[p + 2], jD = col[p + 3];
            LOAD4(jA, jB, jC, jD)
        }
        int rem = end - p;
        if (q < rem) {
            int jj = col[p + q];
            uint2 v = h4[(size_t)jj * 16 + c];
            float2 lo = __half22float2(__builtin_bit_cast(__half2, v.x));
            float2 hi = __half22float2(__builtin_bit_cast(__half2, v.y));
            a0 += lo.x; a1 += lo.y; a2 += hi.x; a3 += hi.y;
        }
        a0 += __shfl_xor(a0, 16, 64); a0 += __shfl_xor(a0, 32, 64);
        a1 += __shfl_xor(a1, 16, 64); a1 += __shfl_xor(a1, 32, 64);
        a2 += __shfl_xor(a2, 16, 64); a2 += __shfl_xor(a2, 32, 64);
        a3 += __shfl_xor(a3, 16, 64); a3 += __shfl_xor(a3, 32, 64);
        if (lane < 16)
            ((float4*)agg)[i * 16 + c] = make_float4(a0, a1, a2, a3);
    }
}

// ---------------- dense per-node matvec kernels ----------------
// h0 = relu(x @ Wnh + bnh);  base = h0 + bmh + (ea_agg + 1s) @ Wmh[128:144]
__global__ void k_h0base(const float* __restrict__ x, const float* __restrict__ ea,
                         const float* __restrict__ Wnh, const float* __restrict__ bnh,
                         const float* __restrict__ Wmh, const float* __restrict__ bmh,
                         float* __restrict__ h0out, __half* __restrict__ h0out16,
                         float* __restrict__ baseout) {
    __shared__ __align__(16) float sx[4][FDIM];
    __shared__ __align__(16) float sea[4][EDIM];
    int lane = threadIdx.x & 63;
    int wid  = threadIdx.x >> 6;
    float wnh[FDIM], w3[EDIM];
#pragma unroll
    for (int m = 0; m < FDIM; m++) wnh[m] = Wnh[m * FDIM + lane];
    float csum = 0.f;
#pragma unroll
    for (int m = 0; m < EDIM; m++) {
        w3[m] = Wmh[(2 * FDIM + m) * FDIM + lane];
        csum += w3[m];
    }
    float bnhk = bnh[lane], bmhk = bmh[lane];
    int gw = blockIdx.x * 4 + wid;
    int nw = gridDim.x * 4;
    for (int i = gw; i < N_NODES; i += nw) {
        sx[wid][lane] = x[i * FDIM + lane];
        if (lane < EDIM) sea[wid][lane] = ea[i * EDIM + lane];
        float acc = bnhk;
        const float4* s4 = (const float4*)sx[wid];
#pragma unroll
        for (int m4 = 0; m4 < FDIM / 4; m4++) {
            float4 v = s4[m4];
            acc = fmaf(v.x, wnh[4 * m4 + 0], acc);
            acc = fmaf(v.y, wnh[4 * m4 + 1], acc);
            acc = fmaf(v.z, wnh[4 * m4 + 2], acc);
            acc = fmaf(v.w, wnh[4 * m4 + 3], acc);
        }
        float h0 = fmaxf(acc, 0.f);
        float b = h0 + bmhk + csum;
        const float4* e4 = (const float4*)sea[wid];
#pragma unroll
        for (int m4 = 0; m4 < EDIM / 4; m4++) {
            float4 v = e4[m4];
            b = fmaf(v.x, w3[4 * m4 + 0], b);
            b = fmaf(v.y, w3[4 * m4 + 1], b);
            b = fmaf(v.z, w3[4 * m4 + 2], b);
            b = fmaf(v.w, w3[4 * m4 + 3], b);
        }
        h0out[i * FDIM + lane]   = h0;
        h0out16[i * FDIM + lane] = __float2half(h0);
        baseout[i * FDIM + lane] = b;
    }
}

// obase = (aggX + x[i]) @ Wom[128:192] + bom
__global__ void k_obase_mv(const float* __restrict__ agg, const float* __restrict__ x,
                           const float* __restrict__ Wom, const float* __restrict__ bom,
                           float* __restrict__ obase) {
    __shared__ __align__(16) float2 sf2[4][FDIM / 2];
    int lane = threadIdx.x & 63, wid = threadIdx.x >> 6;
    int c = lane & 31;
    float w3[FDIM];
#pragma unroll
    for (int m = 0; m < FDIM; m++) w3[m] = Wom[(2 * FDIM + m) * FDIM + lane];
    float bk = bom[lane];
    int gw = blockIdx.x * 4 + wid, nw = gridDim.x * 4;
    for (int i = gw; i < N_NODES; i += nw) {
        if (lane < 32) {
            float2 xv = ((const float2*)(x + i * FDIM))[c];
            float2 ag = ((const float2*)(agg + i * FDIM))[c];
            sf2[wid][c] = make_float2(ag.x + xv.x, ag.y + xv.y);
        }
        float acc = bk;
        const float4* s4 = (const float4*)sf2[wid];
#pragma unroll
        for (int m4 = 0; m4 < FDIM / 4; m4++) {
            float4 v = s4[m4];
            acc = fmaf(v.x, w3[4 * m4 + 0], acc);
            acc = fmaf(v.y, w3[4 * m4 + 1], acc);
            acc = fmaf(v.z, w3[4 * m4 + 2], acc);
            acc = fmaf(v.w, w3[4 * m4 + 3], acc);
        }
        obase[i * FDIM + lane] = acc;
    }
}

// h_out = relu( (deg*h)@W1 + (agg+h)@W2 + base )
__global__ void k_mv(const float* __restrict__ agg, const float* __restrict__ hin32,
                     const float* __restrict__ base, const int* __restrict__ rowp,
                     const float* __restrict__ Wmh,
                     float* __restrict__ hout32, __half* __restrict__ hout16) {
    __shared__ __align__(16) float4 sm4[4][FDIM / 2];
    int lane = threadIdx.x & 63, wid = threadIdx.x >> 6;
    int c = lane & 31;
    float w1[FDIM], w2[FDIM];
#pragma unroll
    for (int m = 0; m < FDIM; m++) {
        w1[m] = Wmh[m * FDIM + lane];
        w2[m] = Wmh[(FDIM + m) * FDIM + lane];
    }
    int gw = blockIdx.x * 4 + wid, nw = gridDim.x * 4;
    for (int i = gw; i < N_NODES; i += nw) {
        float degf = (float)(rowp[i + 1] - rowp[i] + 1);
        if (lane < 32) {
            float2 hv = ((const float2*)(hin32 + i * FDIM))[c];
            float2 ag = ((const float2*)(agg + i * FDIM))[c];
            sm4[wid][c] = make_float4(degf * hv.x, ag.x + hv.x,
                                      degf * hv.y, ag.y + hv.y);
        }
        float acc = base[i * FDIM + lane];
        const float4* s4 = (const float4*)sm4[wid];
#pragma unroll
        for (int m2 = 0; m2 < 32; m2++) {
            float4 v = s4[m2];
            acc = fmaf(v.x, w1[2 * m2], acc);
            acc = fmaf(v.y, w2[2 * m2], acc);
            acc = fmaf(v.z, w1[2 * m2 + 1], acc);
            acc = fmaf(v.w, w2[2 * m2 + 1], acc);
        }
        float h = fmaxf(acc, 0.f);
        hout32[i * FDIM + lane] = h;
        hout16[i * FDIM + lane] = __float2half(h);
    }
}

// out = relu( (deg*h)@Wom1 + (agg+h)@Wom2 + obase ); dot Wout; atomic pool
__global__ void k_out_mv(const float* __restrict__ agg, const float* __restrict__ hin32,
                         const float* __restrict__ obase, const int* __restrict__ rowp,
                         const float* __restrict__ Wom, const float* __restrict__ Wout,
                         const int* __restrict__ batch, float* __restrict__ dout) {
    __shared__ __align__(16) float4 sm4[4][FDIM / 2];
    int lane = threadIdx.x & 63, wid = threadIdx.x >> 6;
    int c = lane & 31;
    float w1[FDIM], w2[FDIM];
#pragma unroll
    for (int m = 0; m < FDIM; m++) {
        w1[m] = Wom[m * FDIM + lane];
        w2[m] = Wom[(FDIM + m) * FDIM + lane];
    }
    float wo = Wout[lane];
    int gw = blockIdx.x * 4 + wid, nw = gridDim.x * 4;
    for (int i = gw; i < N_NODES; i += nw) {
        float degf = (float)(rowp[i + 1] - rowp[i] + 1);
        if (lane < 32) {
            float2 hv = ((const float2*)(hin32 + i * FDIM))[c];
            float2 ag = ((const float2*)(agg + i * FDIM))[c];
            sm4[wid][c] = make_float4(degf * hv.x, ag.x + hv.x,
                                      degf * hv.y, ag.y + hv.y);
        }
        float acc = obase[i * FDIM + lane];
        const float4* s4 = (const float4*)sm4[wid];
#pragma unroll
        for (int m2 = 0; m2 < 32; m2++) {
            float4 v = s4[m2];
            acc = fmaf(v.x, w1[2 * m2], acc);
            acc = fmaf(v.y, w2[2 * m2], acc);
            acc = fmaf(v.z, w1[2 * m2 + 1], acc);
            acc = fmaf(v.w, w2[2 * m2 + 1], acc);
        }
        float outk = fmaxf(acc, 0.f);
        float cc = outk * wo;
#pragma unroll
        for (int off = 32; off > 0; off >>= 1) cc += __shfl_down(cc, off, 64);
        if (lane == 0) atomicAdd(&dout[batch[i]], cc);
    }
}

// ---------------- launcher ----------------

extern "C" void kernel_launch(void* const* d_in, const int* in_sizes, int n_in,
                              void* d_out, int out_size, void* d_ws, size_t ws_size,
                              hipStream_t stream) {
    const float* x         = (const float*)d_in[0];
    const float* edge_attr = (const float*)d_in[1];
    const float* Wnh       = (const float*)d_in[2];
    const float* bnh       = (const float*)d_in[3];
    const float* Wmh       = (const float*)d_in[4];
    const float* bmh       = (const float*)d_in[5];
    const float* Wom       = (const float*)d_in[6];
    const float* bom       = (const float*)d_in[7];
    const float* Wout      = (const float*)d_in[8];
    const float* bout      = (const float*)d_in[9];
    const int*   eidx      = (const int*)d_in[10];
    const int*   batch     = (const int*)d_in[11];
    const int*   srcI = eidx;             // edge_index[0] : source (x_j)
    const int*   dstI = eidx + N_EDGES;   // edge_index[1] : target (aggregation)
    float* out = (float*)d_out;
    (void)in_sizes; (void)n_in; (void)out_size;

    char* w = (char*)d_ws;
    size_t off = 0;
    auto take = [&](size_t b) -> void* {
        void* p = w + off;
        off = (off + b + 255) & ~(size_t)255;
        return p;
    };
    float*  ea    = (float*)take((size_t)N_NODES * EDIM * 4);
    int*    cnt   = (int*)take((size_t)N_NODES * 4);
    int*    rowp  = (int*)take((size_t)(N_NODES + 1) * 4);
    int*    cur   = (int*)take((size_t)N_NODES * 4);
    int*    col   = (int*)take((size_t)N_EDGES * 4);
    int*    eperm = (int*)take((size_t)N_EDGES * 4);
    float*  base  = (float*)take((size_t)N_NODES * FDIM * 4);
    float*  obase = (float*)take((size_t)N_NODES * FDIM * 4);
    float*  hA    = (float*)take((size_t)N_NODES * FDIM * 4);
    float*  hB    = (float*)take((size_t)N_NODES * FDIM * 4);
    float*  agg   = (float*)take((size_t)N_NODES * FDIM * 4);
    __half* x16   = (__half*)take((size_t)N_NODES * FDIM * 2);
    __half* hA16  = (__half*)take((size_t)N_NODES * FDIM * 2);
    __half* hB16  = (__half*)take((size_t)N_NODES * FDIM * 2);
    (void)ws_size;

    hipMemsetAsync(cnt, 0, (size_t)N_NODES * 4, stream);
    k_init_out<<<1, 256, 0, stream>>>(out, bout);
    k_count<<<(N_EDGES + 255) / 256, 256, 0, stream>>>(dstI, cnt);
    k_cvt_x<<<(N_NODES * FDIM + 255) / 256, 256, 0, stream>>>(x, x16);
    k_scan<<<1, 1024, 0, stream>>>(cnt, rowp, cur);
    k_fill<<<(N_EDGES + 255) / 256, 256, 0, stream>>>(srcI, dstI, cur, col, eperm);
    k_ea_agg<<<2048, 256, 0, stream>>>(edge_attr, rowp, eperm, ea);
    k_h0base<<<2048, 256, 0, stream>>>(x, ea, Wnh, bnh, Wmh, bmh, hA, hA16, base);

    k_gather<<<2048, 256, 0, stream>>>(x16, rowp, col, agg);
    k_obase_mv<<<2048, 256, 0, stream>>>(agg, x, Wom, bom, obase);

    k_gather<<<2048, 256, 0, stream>>>(hA16, rowp, col, agg);
    k_mv<<<2048, 256, 0, stream>>>(agg, hA, base, rowp, Wmh, hB, hB16);

    k_gather<<<2048, 256, 0, stream>>>(hB16, rowp, col, agg);
    k_mv<<<2048, 256, 0, stream>>>(agg, hB, base, rowp, Wmh, hA, hA16);

    k_gather<<<2048, 256, 0, stream>>>(hA16, rowp, col, agg);
    k_mv<<<2048, 256, 0, stream>>>(agg, hA, base, rowp, Wmh, hB, hB16);

    k_gather<<<2048, 256, 0, stream>>>(hB16, rowp, col, agg);
    k_out_mv<<<2048, 256, 0, stream>>>(agg, hB, obase, rowp, Wom, Wout, batch, out);
}

// Round 6
// 847.493 us; speedup vs baseline: 1.2043x; 1.2043x over previous
//
#include <hip/hip_runtime.h>
#include <hip/hip_fp16.h>

#define N_NODES 50000
#define N_EDGES 800000
#define NGRAPH  256
#define FDIM    64
#define EDIM    16
#define NBLK    ((N_NODES + 255) / 256)

// ---------------- small setup kernels ----------------

__global__ void k_count(const int* __restrict__ dst, int* __restrict__ cnt) {
    int e = blockIdx.x * blockDim.x + threadIdx.x;
    if (e < N_EDGES) atomicAdd(&cnt[dst[e]], 1);
}

__global__ void k_cvt_x(const float* __restrict__ x, __half* __restrict__ x16) {
    int t = blockIdx.x * blockDim.x + threadIdx.x;
    if (t < N_NODES * FDIM) x16[t] = __float2half(x[t]);
}

// --- coalesced 3-phase exclusive scan of cnt -> rowp, cur ---
__global__ void k_blksum(const int* __restrict__ cnt, int* __restrict__ blksum) {
    __shared__ int red[4];
    int b = blockIdx.x, t = threadIdx.x;
    int idx = b * 256 + t;
    int s = (idx < N_NODES) ? cnt[idx] : 0;
#pragma unroll
    for (int off = 32; off > 0; off >>= 1) s += __shfl_down(s, off, 64);
    int lane = t & 63, wid = t >> 6;
    if (lane == 0) red[wid] = s;
    __syncthreads();
    if (t == 0) blksum[b] = red[0] + red[1] + red[2] + red[3];
}

__global__ void k_scanblk(const int* __restrict__ blksum, int* __restrict__ boff,
                          int* __restrict__ rowp) {
    __shared__ int sh[256];
    int t = threadIdx.x;
    sh[t] = (t < NBLK) ? blksum[t] : 0;
    __syncthreads();
    for (int off = 1; off < 256; off <<= 1) {
        int v = (t >= off) ? sh[t - off] : 0;
        __syncthreads();
        sh[t] += v;
        __syncthreads();
    }
    if (t < NBLK) boff[t] = (t == 0) ? 0 : sh[t - 1];
    if (t == 0) rowp[N_NODES] = sh[255];
}

__global__ void k_rowp(const int* __restrict__ cnt, const int* __restrict__ boff,
                       int* __restrict__ rowp, int* __restrict__ cur) {
    __shared__ int sh[256];
    int b = blockIdx.x, t = threadIdx.x;
    int idx = b * 256 + t;
    int v = (idx < N_NODES) ? cnt[idx] : 0;
    sh[t] = v;
    __syncthreads();
    for (int off = 1; off < 256; off <<= 1) {
        int u = (t >= off) ? sh[t - off] : 0;
        __syncthreads();
        sh[t] += u;
        __syncthreads();
    }
    if (idx < N_NODES) {
        int excl = sh[t] - v + boff[b];
        rowp[idx] = excl;
        cur[idx]  = excl;
    }
}

// fill CSR col + edge permutation
__global__ void k_fill(const int* __restrict__ src, const int* __restrict__ dst,
                       int* __restrict__ cur, int* __restrict__ col,
                       int* __restrict__ eperm) {
    int e = blockIdx.x * blockDim.x + threadIdx.x;
    if (e < N_EDGES) {
        int pos = atomicAdd(&cur[dst[e]], 1);
        col[pos] = src[e];
        eperm[pos] = e;
    }
}

// ea[i] = sum of edge_attr rows of in-edges. Vector-loaded indices + bpermute
// broadcast: 16 edges per load instruction (4 lanes x float4 per 64B row),
// all of a node's loads issue back-to-back (no scalar-load serial chain).
__global__ __launch_bounds__(256, 8) void k_ea_agg(
    const float* __restrict__ edge_attr,
    const int* __restrict__ rowp, const int* __restrict__ eperm,
    float* __restrict__ ea) {
    int lane = threadIdx.x & 63, wid = threadIdx.x >> 6;
    int q = lane >> 2;   // 16 edge-groups
    int c = lane & 3;    // float4 slot in row
    const float4* a4p = (const float4*)edge_attr;
    int gw = blockIdx.x * 4 + wid, nw = gridDim.x * 4;
    for (int i = gw; i < N_NODES; i += nw) {
        int beg = rowp[i], end = rowp[i + 1];
        float x0 = 0.f, x1 = 0.f, x2 = 0.f, x3 = 0.f;
        for (int p = beg; p < end; p += 64) {
            int m = end - p; if (m > 64) m = 64;
            int cidx = p + lane; if (cidx > end - 1) cidx = end - 1;
            int vj = eperm[cidx];
#pragma unroll
            for (int k = 0; k < 4; k++) {
                int e = __shfl(vj, 16 * k + q, 64);
                float4 v = make_float4(0.f, 0.f, 0.f, 0.f);
                if (16 * k + q < m) v = a4p[(size_t)e * 4 + c];
                x0 += v.x; x1 += v.y; x2 += v.z; x3 += v.w;
            }
        }
#pragma unroll
        for (int msk = 4; msk <= 32; msk <<= 1) {
            x0 += __shfl_xor(x0, msk, 64);
            x1 += __shfl_xor(x1, msk, 64);
            x2 += __shfl_xor(x2, msk, 64);
            x3 += __shfl_xor(x3, msk, 64);
        }
        if (lane < 4) ((float4*)ea)[i * 4 + c] = make_float4(x0, x1, x2, x3);
    }
}

// ---------------- gather: agg[i] = sum_{j in-nbrs} h16[j] ----------------
// 8 lanes per 128B row (uint4 = 8 halves/lane); indices via ONE vector load
// + bpermute broadcast; 8 predicated steps, no branches -> deg/8 row-loads
// in flight back-to-back regardless of degree (avg deg = 16).
__global__ __launch_bounds__(256, 8) void k_gather(
    const __half* __restrict__ h16,
    const int* __restrict__ rowp, const int* __restrict__ col,
    float* __restrict__ agg) {
    int lane = threadIdx.x & 63, wid = threadIdx.x >> 6;
    int q = lane >> 3;   // 8 edge-groups
    int c = lane & 7;    // uint4 slot within row
    const uint4* h8 = (const uint4*)h16;
    int gw = blockIdx.x * 4 + wid, nw = gridDim.x * 4;
    for (int i = gw; i < N_NODES; i += nw) {
        int beg = rowp[i], end = rowp[i + 1];
        float a0 = 0, a1 = 0, a2 = 0, a3 = 0, a4 = 0, a5 = 0, a6 = 0, a7 = 0;
        for (int p = beg; p < end; p += 64) {
            int m = end - p; if (m > 64) m = 64;
            int cidx = p + lane; if (cidx > end - 1) cidx = end - 1;
            int vj = col[cidx];
#pragma unroll
            for (int k = 0; k < 8; k++) {
                int j = __shfl(vj, 8 * k + q, 64);
                uint4 v = make_uint4(0, 0, 0, 0);
                if (8 * k + q < m) v = h8[(size_t)j * 8 + c];
                float2 f0 = __half22float2(__builtin_bit_cast(__half2, v.x));
                float2 f1 = __half22float2(__builtin_bit_cast(__half2, v.y));
                float2 f2 = __half22float2(__builtin_bit_cast(__half2, v.z));
                float2 f3 = __half22float2(__builtin_bit_cast(__half2, v.w));
                a0 += f0.x; a1 += f0.y; a2 += f1.x; a3 += f1.y;
                a4 += f2.x; a5 += f2.y; a6 += f3.x; a7 += f3.y;
            }
        }
#pragma unroll
        for (int msk = 8; msk <= 32; msk <<= 1) {
            a0 += __shfl_xor(a0, msk, 64); a1 += __shfl_xor(a1, msk, 64);
            a2 += __shfl_xor(a2, msk, 64); a3 += __shfl_xor(a3, msk, 64);
            a4 += __shfl_xor(a4, msk, 64); a5 += __shfl_xor(a5, msk, 64);
            a6 += __shfl_xor(a6, msk, 64); a7 += __shfl_xor(a7, msk, 64);
        }
        if (lane < 8) {
            ((float4*)agg)[i * 16 + c * 2 + 0] = make_float4(a0, a1, a2, a3);
            ((float4*)agg)[i * 16 + c * 2 + 1] = make_float4(a4, a5, a6, a7);
        }
    }
}

// ---------------- dense per-node matvec kernels ----------------
__global__ void k_h0base(const float* __restrict__ x, const float* __restrict__ ea,
                         const float* __restrict__ Wnh, const float* __restrict__ bnh,
                         const float* __restrict__ Wmh, const float* __restrict__ bmh,
                         float* __restrict__ h0out, __half* __restrict__ h0out16,
                         float* __restrict__ baseout) {
    __shared__ __align__(16) float sx[4][FDIM];
    __shared__ __align__(16) float sea[4][EDIM];
    int lane = threadIdx.x & 63;
    int wid  = threadIdx.x >> 6;
    float wnh[FDIM], w3[EDIM];
#pragma unroll
    for (int m = 0; m < FDIM; m++) wnh[m] = Wnh[m * FDIM + lane];
    float csum = 0.f;
#pragma unroll
    for (int m = 0; m < EDIM; m++) {
        w3[m] = Wmh[(2 * FDIM + m) * FDIM + lane];
        csum += w3[m];
    }
    float bnhk = bnh[lane], bmhk = bmh[lane];
    int gw = blockIdx.x * 4 + wid;
    int nw = gridDim.x * 4;
    for (int i = gw; i < N_NODES; i += nw) {
        sx[wid][lane] = x[i * FDIM + lane];
        if (lane < EDIM) sea[wid][lane] = ea[i * EDIM + lane];
        float acc = bnhk;
        const float4* s4 = (const float4*)sx[wid];
#pragma unroll
        for (int m4 = 0; m4 < FDIM / 4; m4++) {
            float4 v = s4[m4];
            acc = fmaf(v.x, wnh[4 * m4 + 0], acc);
            acc = fmaf(v.y, wnh[4 * m4 + 1], acc);
            acc = fmaf(v.z, wnh[4 * m4 + 2], acc);
            acc = fmaf(v.w, wnh[4 * m4 + 3], acc);
        }
        float h0 = fmaxf(acc, 0.f);
        float b = h0 + bmhk + csum;
        const float4* e4 = (const float4*)sea[wid];
#pragma unroll
        for (int m4 = 0; m4 < EDIM / 4; m4++) {
            float4 v = e4[m4];
            b = fmaf(v.x, w3[4 * m4 + 0], b);
            b = fmaf(v.y, w3[4 * m4 + 1], b);
            b = fmaf(v.z, w3[4 * m4 + 2], b);
            b = fmaf(v.w, w3[4 * m4 + 3], b);
        }
        h0out[i * FDIM + lane]   = h0;
        h0out16[i * FDIM + lane] = __float2half(h0);
        baseout[i * FDIM + lane] = b;
    }
}

__global__ void k_obase_mv(const float* __restrict__ agg, const float* __restrict__ x,
                           const float* __restrict__ Wom, const float* __restrict__ bom,
                           float* __restrict__ obase) {
    __shared__ __align__(16) float2 sf2[4][FDIM / 2];
    int lane = threadIdx.x & 63, wid = threadIdx.x >> 6;
    int c = lane & 31;
    float w3[FDIM];
#pragma unroll
    for (int m = 0; m < FDIM; m++) w3[m] = Wom[(2 * FDIM + m) * FDIM + lane];
    float bk = bom[lane];
    int gw = blockIdx.x * 4 + wid, nw = gridDim.x * 4;
    for (int i = gw; i < N_NODES; i += nw) {
        if (lane < 32) {
            float2 xv = ((const float2*)(x + i * FDIM))[c];
            float2 ag = ((const float2*)(agg + i * FDIM))[c];
            sf2[wid][c] = make_float2(ag.x + xv.x, ag.y + xv.y);
        }
        float acc = bk;
        const float4* s4 = (const float4*)sf2[wid];
#pragma unroll
        for (int m4 = 0; m4 < FDIM / 4; m4++) {
            float4 v = s4[m4];
            acc = fmaf(v.x, w3[4 * m4 + 0], acc);
            acc = fmaf(v.y, w3[4 * m4 + 1], acc);
            acc = fmaf(v.z, w3[4 * m4 + 2], acc);
            acc = fmaf(v.w, w3[4 * m4 + 3], acc);
        }
        obase[i * FDIM + lane] = acc;
    }
}

__global__ void k_mv(const float* __restrict__ agg, const float* __restrict__ hin32,
                     const float* __restrict__ base, const int* __restrict__ rowp,
                     const float* __restrict__ Wmh,
                     float* __restrict__ hout32, __half* __restrict__ hout16) {
    __shared__ __align__(16) float4 sm4[4][FDIM / 2];
    int lane = threadIdx.x & 63, wid = threadIdx.x >> 6;
    int c = lane & 31;
    float w1[FDIM], w2[FDIM];
#pragma unroll
    for (int m = 0; m < FDIM; m++) {
        w1[m] = Wmh[m * FDIM + lane];
        w2[m] = Wmh[(FDIM + m) * FDIM + lane];
    }
    int gw = blockIdx.x * 4 + wid, nw = gridDim.x * 4;
    for (int i = gw; i < N_NODES; i += nw) {
        float degf = (float)(rowp[i + 1] - rowp[i] + 1);
        if (lane < 32) {
            float2 hv = ((const float2*)(hin32 + i * FDIM))[c];
            float2 ag = ((const float2*)(agg + i * FDIM))[c];
            sm4[wid][c] = make_float4(degf * hv.x, ag.x + hv.x,
                                      degf * hv.y, ag.y + hv.y);
        }
        float acc = base[i * FDIM + lane];
        const float4* s4 = (const float4*)sm4[wid];
#pragma unroll
        for (int m2 = 0; m2 < 32; m2++) {
            float4 v = s4[m2];
            acc = fmaf(v.x, w1[2 * m2], acc);
            acc = fmaf(v.y, w2[2 * m2], acc);
            acc = fmaf(v.z, w1[2 * m2 + 1], acc);
            acc = fmaf(v.w, w2[2 * m2 + 1], acc);
        }
        float h = fmaxf(acc, 0.f);
        hout32[i * FDIM + lane] = h;
        hout16[i * FDIM + lane] = __float2half(h);
    }
}

// per-node scalar sc[i] = relu(...)·Wout  (NO atomics — pooled in k_pool)
__global__ void k_out_mv(const float* __restrict__ agg, const float* __restrict__ hin32,
                         const float* __restrict__ obase, const int* __restrict__ rowp,
                         const float* __restrict__ Wom, const float* __restrict__ Wout,
                         float* __restrict__ sc) {
    __shared__ __align__(16) float4 sm4[4][FDIM / 2];
    int lane = threadIdx.x & 63, wid = threadIdx.x >> 6;
    int c = lane & 31;
    float w1[FDIM], w2[FDIM];
#pragma unroll
    for (int m = 0; m < FDIM; m++) {
        w1[m] = Wom[m * FDIM + lane];
        w2[m] = Wom[(FDIM + m) * FDIM + lane];
    }
    float wo = Wout[lane];
    int gw = blockIdx.x * 4 + wid, nw = gridDim.x * 4;
    for (int i = gw; i < N_NODES; i += nw) {
        float degf = (float)(rowp[i + 1] - rowp[i] + 1);
        if (lane < 32) {
            float2 hv = ((const float2*)(hin32 + i * FDIM))[c];
            float2 ag = ((const float2*)(agg + i * FDIM))[c];
            sm4[wid][c] = make_float4(degf * hv.x, ag.x + hv.x,
                                      degf * hv.y, ag.y + hv.y);
        }
        float acc = obase[i * FDIM + lane];
        const float4* s4 = (const float4*)sm4[wid];
#pragma unroll
        for (int m2 = 0; m2 < 32; m2++) {
            float4 v = s4[m2];
            acc = fmaf(v.x, w1[2 * m2], acc);
            acc = fmaf(v.y, w2[2 * m2], acc);
            acc = fmaf(v.z, w1[2 * m2 + 1], acc);
            acc = fmaf(v.w, w2[2 * m2 + 1], acc);
        }
        float outk = fmaxf(acc, 0.f);
        float cc = outk * wo;
#pragma unroll
        for (int off = 32; off > 0; off >>= 1) cc += __shfl_down(cc, off, 64);
        if (lane == 0) sc[i] = cc;
    }
}

// out[g] = sum over nodes of graph g of sc + b_out. batch is sorted: binary
// search segment bounds; one block per graph; no atomics.
__global__ void k_pool(const float* __restrict__ sc, const int* __restrict__ batch,
                       const float* __restrict__ b_out, float* __restrict__ out) {
    __shared__ float red[4];
    int g = blockIdx.x, t = threadIdx.x;
    int lo = 0, hi = N_NODES;
    while (lo < hi) { int mid = (lo + hi) >> 1; if (batch[mid] < g) lo = mid + 1; else hi = mid; }
    int lo2 = lo, hi2 = N_NODES;
    while (lo2 < hi2) { int mid = (lo2 + hi2) >> 1; if (batch[mid] < g + 1) lo2 = mid + 1; else hi2 = mid; }
    float s = 0.f;
    for (int i = lo + t; i < lo2; i += 256) s += sc[i];
#pragma unroll
    for (int off = 32; off > 0; off >>= 1) s += __shfl_down(s, off, 64);
    int lane = t & 63, wid = t >> 6;
    if (lane == 0) red[wid] = s;
    __syncthreads();
    if (t == 0) out[g] = red[0] + red[1] + red[2] + red[3] + b_out[0];
}

// ---------------- launcher ----------------

extern "C" void kernel_launch(void* const* d_in, const int* in_sizes, int n_in,
                              void* d_out, int out_size, void* d_ws, size_t ws_size,
                              hipStream_t stream) {
    const float* x         = (const float*)d_in[0];
    const float* edge_attr = (const float*)d_in[1];
    const float* Wnh       = (const float*)d_in[2];
    const float* bnh       = (const float*)d_in[3];
    const float* Wmh       = (const float*)d_in[4];
    const float* bmh       = (const float*)d_in[5];
    const float* Wom       = (const float*)d_in[6];
    const float* bom       = (const float*)d_in[7];
    const float* Wout      = (const float*)d_in[8];
    const float* bout      = (const float*)d_in[9];
    const int*   eidx      = (const int*)d_in[10];
    const int*   batch     = (const int*)d_in[11];
    const int*   srcI = eidx;
    const int*   dstI = eidx + N_EDGES;
    float* out = (float*)d_out;
    (void)in_sizes; (void)n_in; (void)out_size;

    char* w = (char*)d_ws;
    size_t off = 0;
    auto take = [&](size_t b) -> void* {
        void* p = w + off;
        off = (off + b + 255) & ~(size_t)255;
        return p;
    };
    float*  ea    = (float*)take((size_t)N_NODES * EDIM * 4);
    int*    cnt   = (int*)take((size_t)N_NODES * 4);
    int*    rowp  = (int*)take((size_t)(N_NODES + 1) * 4);
    int*    cur   = (int*)take((size_t)N_NODES * 4);
    int*    col   = (int*)take((size_t)N_EDGES * 4);
    int*    eperm = (int*)take((size_t)N_EDGES * 4);
    float*  base  = (float*)take((size_t)N_NODES * FDIM * 4);
    float*  obase = (float*)take((size_t)N_NODES * FDIM * 4);
    float*  hA    = (float*)take((size_t)N_NODES * FDIM * 4);
    float*  hB    = (float*)take((size_t)N_NODES * FDIM * 4);
    float*  agg   = (float*)take((size_t)N_NODES * FDIM * 4);
    float*  sc    = (float*)take((size_t)N_NODES * 4);
    int*    blks  = (int*)take(256 * 4);
    int*    boff  = (int*)take(256 * 4);
    __half* x16   = (__half*)take((size_t)N_NODES * FDIM * 2);
    __half* hA16  = (__half*)take((size_t)N_NODES * FDIM * 2);
    __half* hB16  = (__half*)take((size_t)N_NODES * FDIM * 2);
    (void)ws_size;

    hipMemsetAsync(cnt, 0, (size_t)N_NODES * 4, stream);
    k_count<<<(N_EDGES + 255) / 256, 256, 0, stream>>>(dstI, cnt);
    k_cvt_x<<<(N_NODES * FDIM + 255) / 256, 256, 0, stream>>>(x, x16);
    k_blksum<<<NBLK, 256, 0, stream>>>(cnt, blks);
    k_scanblk<<<1, 256, 0, stream>>>(blks, boff, rowp);
    k_rowp<<<NBLK, 256, 0, stream>>>(cnt, boff, rowp, cur);
    k_fill<<<(N_EDGES + 255) / 256, 256, 0, stream>>>(srcI, dstI, cur, col, eperm);
    k_ea_agg<<<2048, 256, 0, stream>>>(edge_attr, rowp, eperm, ea);
    k_h0base<<<2048, 256, 0, stream>>>(x, ea, Wnh, bnh, Wmh, bmh, hA, hA16, base);

    k_gather<<<2048, 256, 0, stream>>>(x16, rowp, col, agg);
    k_obase_mv<<<2048, 256, 0, stream>>>(agg, x, Wom, bom, obase);

    k_gather<<<2048, 256, 0, stream>>>(hA16, rowp, col, agg);
    k_mv<<<2048, 256, 0, stream>>>(agg, hA, base, rowp, Wmh, hB, hB16);

    k_gather<<<2048, 256, 0, stream>>>(hB16, rowp, col, agg);
    k_mv<<<2048, 256, 0, stream>>>(agg, hB, base, rowp, Wmh, hA, hA16);

    k_gather<<<2048, 256, 0, stream>>>(hA16, rowp, col, agg);
    k_mv<<<2048, 256, 0, stream>>>(agg, hA, base, rowp, Wmh, hB, hB16);

    k_gather<<<2048, 256, 0, stream>>>(hB16, rowp, col, agg);
    k_out_mv<<<2048, 256, 0, stream>>>(agg, hB, obase, rowp, Wom, Wout, sc);
    k_pool<<<NGRAPH, 256, 0, stream>>>(sc, batch, bout, out);
}

// Round 7
// 711.193 us; speedup vs baseline: 1.4351x; 1.1916x over previous
//
#include <hip/hip_runtime.h>
#include <hip/hip_fp16.h>

#define N_NODES 50000
#define N_EDGES 800000
#define NGRAPH  256
#define FDIM    64
#define EDIM    16
#define NBLK    ((N_NODES + 255) / 256)

// ---------------- small setup kernels ----------------

__global__ void k_count(const int* __restrict__ dst, int* __restrict__ cnt) {
    int e = blockIdx.x * blockDim.x + threadIdx.x;
    if (e < N_EDGES) atomicAdd(&cnt[dst[e]], 1);
}

__global__ void k_cvt_x(const float* __restrict__ x, __half* __restrict__ x16) {
    int t = blockIdx.x * blockDim.x + threadIdx.x;
    if (t < N_NODES * FDIM) x16[t] = __float2half(x[t]);
}

// --- coalesced 3-phase exclusive scan of cnt -> rowp, cur, degf ---
__global__ void k_blksum(const int* __restrict__ cnt, int* __restrict__ blksum) {
    __shared__ int red[4];
    int b = blockIdx.x, t = threadIdx.x;
    int idx = b * 256 + t;
    int s = (idx < N_NODES) ? cnt[idx] : 0;
#pragma unroll
    for (int off = 32; off > 0; off >>= 1) s += __shfl_down(s, off, 64);
    int lane = t & 63, wid = t >> 6;
    if (lane == 0) red[wid] = s;
    __syncthreads();
    if (t == 0) blksum[b] = red[0] + red[1] + red[2] + red[3];
}

__global__ void k_scanblk(const int* __restrict__ blksum, int* __restrict__ boff,
                          int* __restrict__ rowp) {
    __shared__ int sh[256];
    int t = threadIdx.x;
    sh[t] = (t < NBLK) ? blksum[t] : 0;
    __syncthreads();
    for (int off = 1; off < 256; off <<= 1) {
        int v = (t >= off) ? sh[t - off] : 0;
        __syncthreads();
        sh[t] += v;
        __syncthreads();
    }
    if (t < NBLK) boff[t] = (t == 0) ? 0 : sh[t - 1];
    if (t == 0) rowp[N_NODES] = sh[255];
}

__global__ void k_rowp(const int* __restrict__ cnt, const int* __restrict__ boff,
                       int* __restrict__ rowp, int* __restrict__ cur,
                       float* __restrict__ degf) {
    __shared__ int sh[256];
    int b = blockIdx.x, t = threadIdx.x;
    int idx = b * 256 + t;
    int v = (idx < N_NODES) ? cnt[idx] : 0;
    sh[t] = v;
    __syncthreads();
    for (int off = 1; off < 256; off <<= 1) {
        int u = (t >= off) ? sh[t - off] : 0;
        __syncthreads();
        sh[t] += u;
        __syncthreads();
    }
    if (idx < N_NODES) {
        int excl = sh[t] - v + boff[b];
        rowp[idx] = excl;
        cur[idx]  = excl;
        degf[idx] = (float)(v + 1);   // +1 self loop
    }
}

// fill CSR col + edge permutation
__global__ void k_fill(const int* __restrict__ src, const int* __restrict__ dst,
                       int* __restrict__ cur, int* __restrict__ col,
                       int* __restrict__ eperm) {
    int e = blockIdx.x * blockDim.x + threadIdx.x;
    if (e < N_EDGES) {
        int pos = atomicAdd(&cur[dst[e]], 1);
        col[pos] = src[e];
        eperm[pos] = e;
    }
}

// ea[i] = sum of edge_attr rows of in-edges (self row handled via csum).
__global__ __launch_bounds__(256, 8) void k_ea_agg(
    const float* __restrict__ edge_attr,
    const int* __restrict__ rowp, const int* __restrict__ eperm,
    float* __restrict__ ea) {
    int lane = threadIdx.x & 63, wid = threadIdx.x >> 6;
    int q = lane >> 2;
    int c = lane & 3;
    const float4* a4p = (const float4*)edge_attr;
    int gw = blockIdx.x * 4 + wid, nw = gridDim.x * 4;
    for (int i = gw; i < N_NODES; i += nw) {
        int beg = rowp[i], end = rowp[i + 1];
        float x0 = 0.f, x1 = 0.f, x2 = 0.f, x3 = 0.f;
        for (int p = beg; p < end; p += 64) {
            int m = end - p; if (m > 64) m = 64;
            int cidx = p + lane; if (cidx > end - 1) cidx = end - 1;
            int vj = eperm[cidx];
#pragma unroll
            for (int k = 0; k < 4; k++) {
                int e = __shfl(vj, 16 * k + q, 64);
                float4 v = make_float4(0.f, 0.f, 0.f, 0.f);
                if (16 * k + q < m) v = a4p[(size_t)e * 4 + c];
                x0 += v.x; x1 += v.y; x2 += v.z; x3 += v.w;
            }
        }
#pragma unroll
        for (int msk = 4; msk <= 32; msk <<= 1) {
            x0 += __shfl_xor(x0, msk, 64);
            x1 += __shfl_xor(x1, msk, 64);
            x2 += __shfl_xor(x2, msk, 64);
            x3 += __shfl_xor(x3, msk, 64);
        }
        if (lane < 4) ((float4*)ea)[i * 4 + c] = make_float4(x0, x1, x2, x3);
    }
}

// ---------------- gather: agg[i] = sum_{j in-nbrs} h16[j] ----------------
__global__ __launch_bounds__(256, 8) void k_gather(
    const __half* __restrict__ h16,
    const int* __restrict__ rowp, const int* __restrict__ col,
    float* __restrict__ agg) {
    int lane = threadIdx.x & 63, wid = threadIdx.x >> 6;
    int q = lane >> 3;
    int c = lane & 7;
    const uint4* h8 = (const uint4*)h16;
    int gw = blockIdx.x * 4 + wid, nw = gridDim.x * 4;
    for (int i = gw; i < N_NODES; i += nw) {
        int beg = rowp[i], end = rowp[i + 1];
        float a0 = 0, a1 = 0, a2 = 0, a3 = 0, a4 = 0, a5 = 0, a6 = 0, a7 = 0;
        for (int p = beg; p < end; p += 64) {
            int m = end - p; if (m > 64) m = 64;
            int cidx = p + lane; if (cidx > end - 1) cidx = end - 1;
            int vj = col[cidx];
#pragma unroll
            for (int k = 0; k < 8; k++) {
                int j = __shfl(vj, 8 * k + q, 64);
                uint4 v = make_uint4(0, 0, 0, 0);
                if (8 * k + q < m) v = h8[(size_t)j * 8 + c];
                float2 f0 = __half22float2(__builtin_bit_cast(__half2, v.x));
                float2 f1 = __half22float2(__builtin_bit_cast(__half2, v.y));
                float2 f2 = __half22float2(__builtin_bit_cast(__half2, v.z));
                float2 f3 = __half22float2(__builtin_bit_cast(__half2, v.w));
                a0 += f0.x; a1 += f0.y; a2 += f1.x; a3 += f1.y;
                a4 += f2.x; a5 += f2.y; a6 += f3.x; a7 += f3.y;
            }
        }
#pragma unroll
        for (int msk = 8; msk <= 32; msk <<= 1) {
            a0 += __shfl_xor(a0, msk, 64); a1 += __shfl_xor(a1, msk, 64);
            a2 += __shfl_xor(a2, msk, 64); a3 += __shfl_xor(a3, msk, 64);
            a4 += __shfl_xor(a4, msk, 64); a5 += __shfl_xor(a5, msk, 64);
            a6 += __shfl_xor(a6, msk, 64); a7 += __shfl_xor(a7, msk, 64);
        }
        if (lane < 8) {
            ((float4*)agg)[i * 16 + c * 2 + 0] = make_float4(a0, a1, a2, a3);
            ((float4*)agg)[i * 16 + c * 2 + 1] = make_float4(a4, a5, a6, a7);
        }
    }
}

// ---------------- dense per-node matvec kernels (4-acc ILP) ----------------
// h0 = relu(x @ Wnh + bnh);  base = h0 + bmh + (ea_agg + 1s) @ Wmh[128:144]
__global__ void k_h0base(const float* __restrict__ x, const float* __restrict__ ea,
                         const float* __restrict__ Wnh, const float* __restrict__ bnh,
                         const float* __restrict__ Wmh, const float* __restrict__ bmh,
                         __half* __restrict__ h0out16, float* __restrict__ baseout) {
    __shared__ __align__(16) float sx[4][FDIM];
    __shared__ __align__(16) float sea[4][EDIM];
    int lane = threadIdx.x & 63;
    int wid  = threadIdx.x >> 6;
    float wnh[FDIM], w3[EDIM];
#pragma unroll
    for (int m = 0; m < FDIM; m++) wnh[m] = Wnh[m * FDIM + lane];
    float csum = 0.f;
#pragma unroll
    for (int m = 0; m < EDIM; m++) {
        w3[m] = Wmh[(2 * FDIM + m) * FDIM + lane];
        csum += w3[m];
    }
    float bnhk = bnh[lane], bmhk = bmh[lane];
    int gw = blockIdx.x * 4 + wid;
    int nw = gridDim.x * 4;
    for (int i = gw; i < N_NODES; i += nw) {
        sx[wid][lane] = x[i * FDIM + lane];
        if (lane < EDIM) sea[wid][lane] = ea[i * EDIM + lane];
        float acc0 = bnhk, acc1 = 0.f, acc2 = 0.f, acc3 = 0.f;
        const float4* s4 = (const float4*)sx[wid];
#pragma unroll
        for (int m4 = 0; m4 < FDIM / 4; m4++) {
            float4 v = s4[m4];
            acc0 = fmaf(v.x, wnh[4 * m4 + 0], acc0);
            acc1 = fmaf(v.y, wnh[4 * m4 + 1], acc1);
            acc2 = fmaf(v.z, wnh[4 * m4 + 2], acc2);
            acc3 = fmaf(v.w, wnh[4 * m4 + 3], acc3);
        }
        float h0 = fmaxf((acc0 + acc2) + (acc1 + acc3), 0.f);
        float b0 = h0 + bmhk + csum, b1 = 0.f, b2 = 0.f, b3 = 0.f;
        const float4* e4 = (const float4*)sea[wid];
#pragma unroll
        for (int m4 = 0; m4 < EDIM / 4; m4++) {
            float4 v = e4[m4];
            b0 = fmaf(v.x, w3[4 * m4 + 0], b0);
            b1 = fmaf(v.y, w3[4 * m4 + 1], b1);
            b2 = fmaf(v.z, w3[4 * m4 + 2], b2);
            b3 = fmaf(v.w, w3[4 * m4 + 3], b3);
        }
        h0out16[i * FDIM + lane] = __float2half(h0);
        baseout[i * FDIM + lane] = (b0 + b2) + (b1 + b3);
    }
}

// obase = (aggX + x[i]) @ Wom[128:192] + bom
__global__ void k_obase_mv(const float* __restrict__ agg, const __half* __restrict__ x16,
                           const float* __restrict__ Wom, const float* __restrict__ bom,
                           float* __restrict__ obase) {
    __shared__ __align__(16) float2 sf2[4][FDIM / 2];
    int lane = threadIdx.x & 63, wid = threadIdx.x >> 6;
    int c = lane & 31;
    float w3[FDIM];
#pragma unroll
    for (int m = 0; m < FDIM; m++) w3[m] = Wom[(2 * FDIM + m) * FDIM + lane];
    float bk = bom[lane];
    int gw = blockIdx.x * 4 + wid, nw = gridDim.x * 4;
    for (int i = gw; i < N_NODES; i += nw) {
        if (lane < 32) {
            float2 xv = __half22float2(((const __half2*)x16)[i * 32 + c]);
            float2 ag = ((const float2*)(agg + i * FDIM))[c];
            sf2[wid][c] = make_float2(ag.x + xv.x, ag.y + xv.y);
        }
        float acc0 = bk, acc1 = 0.f, acc2 = 0.f, acc3 = 0.f;
        const float4* s4 = (const float4*)sf2[wid];
#pragma unroll
        for (int m4 = 0; m4 < FDIM / 4; m4++) {
            float4 v = s4[m4];
            acc0 = fmaf(v.x, w3[4 * m4 + 0], acc0);
            acc1 = fmaf(v.y, w3[4 * m4 + 1], acc1);
            acc2 = fmaf(v.z, w3[4 * m4 + 2], acc2);
            acc3 = fmaf(v.w, w3[4 * m4 + 3], acc3);
        }
        obase[i * FDIM + lane] = (acc0 + acc2) + (acc1 + acc3);
    }
}

// h_out16 = relu( (deg*h)@W1 + (agg+h)@W2 + base ), h self-row from fp16
__global__ void k_mv(const float* __restrict__ agg, const __half* __restrict__ hin16,
                     const float* __restrict__ base, const float* __restrict__ degf,
                     const float* __restrict__ Wmh, __half* __restrict__ hout16) {
    __shared__ __align__(16) float4 sm4[4][FDIM / 2];
    int lane = threadIdx.x & 63, wid = threadIdx.x >> 6;
    int c = lane & 31;
    float w1[FDIM], w2[FDIM];
#pragma unroll
    for (int m = 0; m < FDIM; m++) {
        w1[m] = Wmh[m * FDIM + lane];
        w2[m] = Wmh[(FDIM + m) * FDIM + lane];
    }
    int gw = blockIdx.x * 4 + wid, nw = gridDim.x * 4;
    for (int i = gw; i < N_NODES; i += nw) {
        float dg = degf[i];
        if (lane < 32) {
            float2 hv = __half22float2(((const __half2*)hin16)[i * 32 + c]);
            float2 ag = ((const float2*)(agg + i * FDIM))[c];
            sm4[wid][c] = make_float4(dg * hv.x, ag.x + hv.x,
                                      dg * hv.y, ag.y + hv.y);
        }
        float acc0 = base[i * FDIM + lane], acc1 = 0.f, acc2 = 0.f, acc3 = 0.f;
        const float4* s4 = (const float4*)sm4[wid];
#pragma unroll
        for (int m2 = 0; m2 < 32; m2++) {
            float4 v = s4[m2];
            acc0 = fmaf(v.x, w1[2 * m2], acc0);
            acc1 = fmaf(v.y, w2[2 * m2], acc1);
            acc2 = fmaf(v.z, w1[2 * m2 + 1], acc2);
            acc3 = fmaf(v.w, w2[2 * m2 + 1], acc3);
        }
        float h = fmaxf((acc0 + acc2) + (acc1 + acc3), 0.f);
        hout16[i * FDIM + lane] = __float2half(h);
    }
}

// per-node scalar sc[i] = relu((deg*h)@Wom1 + (agg+h)@Wom2 + obase)·Wout
__global__ void k_out_mv(const float* __restrict__ agg, const __half* __restrict__ hin16,
                         const float* __restrict__ obase, const float* __restrict__ degf,
                         const float* __restrict__ Wom, const float* __restrict__ Wout,
                         float* __restrict__ sc) {
    __shared__ __align__(16) float4 sm4[4][FDIM / 2];
    int lane = threadIdx.x & 63, wid = threadIdx.x >> 6;
    int c = lane & 31;
    float w1[FDIM], w2[FDIM];
#pragma unroll
    for (int m = 0; m < FDIM; m++) {
        w1[m] = Wom[m * FDIM + lane];
        w2[m] = Wom[(FDIM + m) * FDIM + lane];
    }
    float wo = Wout[lane];
    int gw = blockIdx.x * 4 + wid, nw = gridDim.x * 4;
    for (int i = gw; i < N_NODES; i += nw) {
        float dg = degf[i];
        if (lane < 32) {
            float2 hv = __half22float2(((const __half2*)hin16)[i * 32 + c]);
            float2 ag = ((const float2*)(agg + i * FDIM))[c];
            sm4[wid][c] = make_float4(dg * hv.x, ag.x + hv.x,
                                      dg * hv.y, ag.y + hv.y);
        }
        float acc0 = obase[i * FDIM + lane], acc1 = 0.f, acc2 = 0.f, acc3 = 0.f;
        const float4* s4 = (const float4*)sm4[wid];
#pragma unroll
        for (int m2 = 0; m2 < 32; m2++) {
            float4 v = s4[m2];
            acc0 = fmaf(v.x, w1[2 * m2], acc0);
            acc1 = fmaf(v.y, w2[2 * m2], acc1);
            acc2 = fmaf(v.z, w1[2 * m2 + 1], acc2);
            acc3 = fmaf(v.w, w2[2 * m2 + 1], acc3);
        }
        float outk = fmaxf((acc0 + acc2) + (acc1 + acc3), 0.f);
        float cc = outk * wo;
#pragma unroll
        for (int off = 32; off > 0; off >>= 1) cc += __shfl_down(cc, off, 64);
        if (lane == 0) sc[i] = cc;
    }
}

// out[g] = sum of sc over graph-g nodes + b_out (batch sorted, binary search)
__global__ void k_pool(const float* __restrict__ sc, const int* __restrict__ batch,
                       const float* __restrict__ b_out, float* __restrict__ out) {
    __shared__ float red[4];
    int g = blockIdx.x, t = threadIdx.x;
    int lo = 0, hi = N_NODES;
    while (lo < hi) { int mid = (lo + hi) >> 1; if (batch[mid] < g) lo = mid + 1; else hi = mid; }
    int lo2 = lo, hi2 = N_NODES;
    while (lo2 < hi2) { int mid = (lo2 + hi2) >> 1; if (batch[mid] < g + 1) lo2 = mid + 1; else hi2 = mid; }
    float s = 0.f;
    for (int i = lo + t; i < lo2; i += 256) s += sc[i];
#pragma unroll
    for (int off = 32; off > 0; off >>= 1) s += __shfl_down(s, off, 64);
    int lane = t & 63, wid = t >> 6;
    if (lane == 0) red[wid] = s;
    __syncthreads();
    if (t == 0) out[g] = red[0] + red[1] + red[2] + red[3] + b_out[0];
}

// ---------------- launcher ----------------

extern "C" void kernel_launch(void* const* d_in, const int* in_sizes, int n_in,
                              void* d_out, int out_size, void* d_ws, size_t ws_size,
                              hipStream_t stream) {
    const float* x         = (const float*)d_in[0];
    const float* edge_attr = (const float*)d_in[1];
    const float* Wnh       = (const float*)d_in[2];
    const float* bnh       = (const float*)d_in[3];
    const float* Wmh       = (const float*)d_in[4];
    const float* bmh       = (const float*)d_in[5];
    const float* Wom       = (const float*)d_in[6];
    const float* bom       = (const float*)d_in[7];
    const float* Wout      = (const float*)d_in[8];
    const float* bout      = (const float*)d_in[9];
    const int*   eidx      = (const int*)d_in[10];
    const int*   batch     = (const int*)d_in[11];
    const int*   srcI = eidx;
    const int*   dstI = eidx + N_EDGES;
    float* out = (float*)d_out;
    (void)in_sizes; (void)n_in; (void)out_size;

    char* w = (char*)d_ws;
    size_t off = 0;
    auto take = [&](size_t b) -> void* {
        void* p = w + off;
        off = (off + b + 255) & ~(size_t)255;
        return p;
    };
    float*  ea    = (float*)take((size_t)N_NODES * EDIM * 4);
    int*    cnt   = (int*)take((size_t)N_NODES * 4);
    int*    rowp  = (int*)take((size_t)(N_NODES + 1) * 4);
    int*    cur   = (int*)take((size_t)N_NODES * 4);
    float*  degf  = (float*)take((size_t)N_NODES * 4);
    int*    col   = (int*)take((size_t)N_EDGES * 4);
    int*    eperm = (int*)take((size_t)N_EDGES * 4);
    float*  base  = (float*)take((size_t)N_NODES * FDIM * 4);
    float*  obase = (float*)take((size_t)N_NODES * FDIM * 4);
    float*  agg   = (float*)take((size_t)N_NODES * FDIM * 4);
    float*  sc    = (float*)take((size_t)N_NODES * 4);
    int*    blks  = (int*)take(256 * 4);
    int*    boff  = (int*)take(256 * 4);
    __half* x16   = (__half*)take((size_t)N_NODES * FDIM * 2);
    __half* hA16  = (__half*)take((size_t)N_NODES * FDIM * 2);
    __half* hB16  = (__half*)take((size_t)N_NODES * FDIM * 2);
    (void)ws_size;

    hipMemsetAsync(cnt, 0, (size_t)N_NODES * 4, stream);
    k_count<<<(N_EDGES + 255) / 256, 256, 0, stream>>>(dstI, cnt);
    k_cvt_x<<<(N_NODES * FDIM + 255) / 256, 256, 0, stream>>>(x, x16);
    k_blksum<<<NBLK, 256, 0, stream>>>(cnt, blks);
    k_scanblk<<<1, 256, 0, stream>>>(blks, boff, rowp);
    k_rowp<<<NBLK, 256, 0, stream>>>(cnt, boff, rowp, cur, degf);
    k_fill<<<(N_EDGES + 255) / 256, 256, 0, stream>>>(srcI, dstI, cur, col, eperm);

    k_gather<<<2048, 256, 0, stream>>>(x16, rowp, col, agg);     // aggX (x16 L2-warm)
    k_obase_mv<<<2048, 256, 0, stream>>>(agg, x16, Wom, bom, obase);
    k_ea_agg<<<2048, 256, 0, stream>>>(edge_attr, rowp, eperm, ea);
    k_h0base<<<2048, 256, 0, stream>>>(x, ea, Wnh, bnh, Wmh, bmh, hA16, base);

    k_gather<<<2048, 256, 0, stream>>>(hA16, rowp, col, agg);
    k_mv<<<2048, 256, 0, stream>>>(agg, hA16, base, degf, Wmh, hB16);

    k_gather<<<2048, 256, 0, stream>>>(hB16, rowp, col, agg);
    k_mv<<<2048, 256, 0, stream>>>(agg, hB16, base, degf, Wmh, hA16);

    k_gather<<<2048, 256, 0, stream>>>(hA16, rowp, col, agg);
    k_mv<<<2048, 256, 0, stream>>>(agg, hA16, base, degf, Wmh, hB16);

    k_gather<<<2048, 256, 0, stream>>>(hB16, rowp, col, agg);
    k_out_mv<<<2048, 256, 0, stream>>>(agg, hB16, obase, degf, Wom, Wout, sc);
    k_pool<<<NGRAPH, 256, 0, stream>>>(sc, batch, bout, out);
}

// Round 8
// 432.045 us; speedup vs baseline: 2.3623x; 1.6461x over previous
//
#include <hip/hip_runtime.h>
#include <hip/hip_fp16.h>

#define N_NODES 50000
#define N_EDGES 800000
#define NGRAPH  256
#define FDIM    64
#define EDIM    16
#define NBLK    ((N_NODES + 255) / 256)
#define NT      (N_NODES / 16)      // 3125 node tiles (exact)

using half8  = __attribute__((ext_vector_type(8))) _Float16;
using float4v = __attribute__((ext_vector_type(4))) float;

__device__ __forceinline__ unsigned hadd2u(unsigned a, unsigned b) {
    __half2 r = __hadd2(__builtin_bit_cast(__half2, a), __builtin_bit_cast(__half2, b));
    return __builtin_bit_cast(unsigned, r);
}
__device__ __forceinline__ unsigned hmul2u(unsigned a, __half2 m) {
    __half2 r = __hmul2(__builtin_bit_cast(__half2, a), m);
    return __builtin_bit_cast(unsigned, r);
}

// ---------------- small setup kernels ----------------

__global__ void k_count(const int* __restrict__ dst, int* __restrict__ cnt) {
    int e = blockIdx.x * blockDim.x + threadIdx.x;
    if (e < N_EDGES) atomicAdd(&cnt[dst[e]], 1);
}

__global__ void k_cvt_x(const float* __restrict__ x, __half* __restrict__ x16) {
    int t = blockIdx.x * blockDim.x + threadIdx.x;
    if (t < N_NODES * FDIM) x16[t] = __float2half(x[t]);
}

__global__ void k_blksum(const int* __restrict__ cnt, int* __restrict__ blksum) {
    __shared__ int red[4];
    int b = blockIdx.x, t = threadIdx.x;
    int idx = b * 256 + t;
    int s = (idx < N_NODES) ? cnt[idx] : 0;
#pragma unroll
    for (int off = 32; off > 0; off >>= 1) s += __shfl_down(s, off, 64);
    int lane = t & 63, wid = t >> 6;
    if (lane == 0) red[wid] = s;
    __syncthreads();
    if (t == 0) blksum[b] = red[0] + red[1] + red[2] + red[3];
}

__global__ void k_scanblk(const int* __restrict__ blksum, int* __restrict__ boff,
                          int* __restrict__ rowp) {
    __shared__ int sh[256];
    int t = threadIdx.x;
    sh[t] = (t < NBLK) ? blksum[t] : 0;
    __syncthreads();
    for (int off = 1; off < 256; off <<= 1) {
        int v = (t >= off) ? sh[t - off] : 0;
        __syncthreads();
        sh[t] += v;
        __syncthreads();
    }
    if (t < NBLK) boff[t] = (t == 0) ? 0 : sh[t - 1];
    if (t == 0) rowp[N_NODES] = sh[255];
}

__global__ void k_rowp(const int* __restrict__ cnt, const int* __restrict__ boff,
                       int* __restrict__ rowp, int* __restrict__ cur,
                       float* __restrict__ degf) {
    __shared__ int sh[256];
    int b = blockIdx.x, t = threadIdx.x;
    int idx = b * 256 + t;
    int v = (idx < N_NODES) ? cnt[idx] : 0;
    sh[t] = v;
    __syncthreads();
    for (int off = 1; off < 256; off <<= 1) {
        int u = (t >= off) ? sh[t - off] : 0;
        __syncthreads();
        sh[t] += u;
        __syncthreads();
    }
    if (idx < N_NODES) {
        int excl = sh[t] - v + boff[b];
        rowp[idx] = excl;
        cur[idx]  = excl;
        degf[idx] = (float)(v + 1);
    }
}

__global__ void k_fill(const int* __restrict__ src, const int* __restrict__ dst,
                       int* __restrict__ cur, int* __restrict__ col,
                       int* __restrict__ eperm) {
    int e = blockIdx.x * blockDim.x + threadIdx.x;
    if (e < N_EDGES) {
        int pos = atomicAdd(&cur[dst[e]], 1);
        col[pos] = src[e];
        eperm[pos] = e;
    }
}

// ea[i] = sum of in-edge edge_attr rows (fp32, small)
__global__ __launch_bounds__(256, 8) void k_ea_agg(
    const float* __restrict__ edge_attr,
    const int* __restrict__ rowp, const int* __restrict__ eperm,
    float* __restrict__ ea) {
    int lane = threadIdx.x & 63, wid = threadIdx.x >> 6;
    int q = lane >> 2;
    int c = lane & 3;
    const float4* a4p = (const float4*)edge_attr;
    int gw = blockIdx.x * 4 + wid, nw = gridDim.x * 4;
    for (int i = gw; i < N_NODES; i += nw) {
        int beg = rowp[i], end = rowp[i + 1];
        float x0 = 0.f, x1 = 0.f, x2 = 0.f, x3 = 0.f;
        for (int p = beg; p < end; p += 64) {
            int m = end - p; if (m > 64) m = 64;
            int cidx = p + lane; if (cidx > end - 1) cidx = end - 1;
            int vj = eperm[cidx];
#pragma unroll
            for (int k = 0; k < 4; k++) {
                int e = __shfl(vj, 16 * k + q, 64);
                float4 v = make_float4(0.f, 0.f, 0.f, 0.f);
                if (16 * k + q < m) v = a4p[(size_t)e * 4 + c];
                x0 += v.x; x1 += v.y; x2 += v.z; x3 += v.w;
            }
        }
#pragma unroll
        for (int msk = 4; msk <= 32; msk <<= 1) {
            x0 += __shfl_xor(x0, msk, 64);
            x1 += __shfl_xor(x1, msk, 64);
            x2 += __shfl_xor(x2, msk, 64);
            x3 += __shfl_xor(x3, msk, 64);
        }
        if (lane < 4) ((float4*)ea)[i * 4 + c] = make_float4(x0, x1, x2, x3);
    }
}

// ---------------- gather: agg16[i] = sum_{j in-nbrs} h16[j] (fp16 out) -----
__global__ __launch_bounds__(256, 8) void k_gather(
    const __half* __restrict__ h16,
    const int* __restrict__ rowp, const int* __restrict__ col,
    __half* __restrict__ agg16) {
    int lane = threadIdx.x & 63, wid = threadIdx.x >> 6;
    int q = lane >> 3;
    int c = lane & 7;
    const uint4* h8 = (const uint4*)h16;
    int gw = blockIdx.x * 4 + wid, nw = gridDim.x * 4;
    for (int i = gw; i < N_NODES; i += nw) {
        int beg = rowp[i], end = rowp[i + 1];
        float a0 = 0, a1 = 0, a2 = 0, a3 = 0, a4 = 0, a5 = 0, a6 = 0, a7 = 0;
        for (int p = beg; p < end; p += 64) {
            int m = end - p; if (m > 64) m = 64;
            int cidx = p + lane; if (cidx > end - 1) cidx = end - 1;
            int vj = col[cidx];
#pragma unroll
            for (int k = 0; k < 8; k++) {
                int j = __shfl(vj, 8 * k + q, 64);
                uint4 v = make_uint4(0, 0, 0, 0);
                if (8 * k + q < m) v = h8[(size_t)j * 8 + c];
                float2 f0 = __half22float2(__builtin_bit_cast(__half2, v.x));
                float2 f1 = __half22float2(__builtin_bit_cast(__half2, v.y));
                float2 f2 = __half22float2(__builtin_bit_cast(__half2, v.z));
                float2 f3 = __half22float2(__builtin_bit_cast(__half2, v.w));
                a0 += f0.x; a1 += f0.y; a2 += f1.x; a3 += f1.y;
                a4 += f2.x; a5 += f2.y; a6 += f3.x; a7 += f3.y;
            }
        }
#pragma unroll
        for (int msk = 8; msk <= 32; msk <<= 1) {
            a0 += __shfl_xor(a0, msk, 64); a1 += __shfl_xor(a1, msk, 64);
            a2 += __shfl_xor(a2, msk, 64); a3 += __shfl_xor(a3, msk, 64);
            a4 += __shfl_xor(a4, msk, 64); a5 += __shfl_xor(a5, msk, 64);
            a6 += __shfl_xor(a6, msk, 64); a7 += __shfl_xor(a7, msk, 64);
        }
        if (lane < 8) {
            __half2 p0 = __floats2half2_rn(a0, a1);
            __half2 p1 = __floats2half2_rn(a2, a3);
            __half2 p2 = __floats2half2_rn(a4, a5);
            __half2 p3 = __floats2half2_rn(a6, a7);
            uint4 o;
            o.x = __builtin_bit_cast(unsigned, p0);
            o.y = __builtin_bit_cast(unsigned, p1);
            o.z = __builtin_bit_cast(unsigned, p2);
            o.w = __builtin_bit_cast(unsigned, p3);
            ((uint4*)agg16)[(size_t)i * 8 + lane] = o;
        }
    }
}

// ---------------- h0/base (VALU, reads fp32 x once) ----------------
__global__ void k_h0base(const float* __restrict__ x, const float* __restrict__ ea,
                         const float* __restrict__ Wnh, const float* __restrict__ bnh,
                         const float* __restrict__ Wmh, const float* __restrict__ bmh,
                         __half* __restrict__ h0out16, __half* __restrict__ base16) {
    __shared__ __align__(16) float sx[4][FDIM];
    __shared__ __align__(16) float sea[4][EDIM];
    int lane = threadIdx.x & 63;
    int wid  = threadIdx.x >> 6;
    float wnh[FDIM], w3[EDIM];
#pragma unroll
    for (int m = 0; m < FDIM; m++) wnh[m] = Wnh[m * FDIM + lane];
    float csum = 0.f;
#pragma unroll
    for (int m = 0; m < EDIM; m++) {
        w3[m] = Wmh[(2 * FDIM + m) * FDIM + lane];
        csum += w3[m];
    }
    float bnhk = bnh[lane], bmhk = bmh[lane];
    int gw = blockIdx.x * 4 + wid;
    int nw = gridDim.x * 4;
    for (int i = gw; i < N_NODES; i += nw) {
        sx[wid][lane] = x[i * FDIM + lane];
        if (lane < EDIM) sea[wid][lane] = ea[i * EDIM + lane];
        float acc0 = bnhk, acc1 = 0.f, acc2 = 0.f, acc3 = 0.f;
        const float4* s4 = (const float4*)sx[wid];
#pragma unroll
        for (int m4 = 0; m4 < FDIM / 4; m4++) {
            float4 v = s4[m4];
            acc0 = fmaf(v.x, wnh[4 * m4 + 0], acc0);
            acc1 = fmaf(v.y, wnh[4 * m4 + 1], acc1);
            acc2 = fmaf(v.z, wnh[4 * m4 + 2], acc2);
            acc3 = fmaf(v.w, wnh[4 * m4 + 3], acc3);
        }
        float h0 = fmaxf((acc0 + acc2) + (acc1 + acc3), 0.f);
        float b0 = h0 + bmhk + csum, b1 = 0.f, b2 = 0.f, b3 = 0.f;
        const float4* e4 = (const float4*)sea[wid];
#pragma unroll
        for (int m4 = 0; m4 < EDIM / 4; m4++) {
            float4 v = e4[m4];
            b0 = fmaf(v.x, w3[4 * m4 + 0], b0);
            b1 = fmaf(v.y, w3[4 * m4 + 1], b1);
            b2 = fmaf(v.z, w3[4 * m4 + 2], b2);
            b3 = fmaf(v.w, w3[4 * m4 + 3], b3);
        }
        h0out16[i * FDIM + lane] = __float2half(h0);
        base16[i * FDIM + lane]  = __float2half((b0 + b2) + (b1 + b3));
    }
}

// ---------------- MFMA mv kernels ----------------
// Per wave: one 16-node tile. S[16][128] fp16 staged in per-wave LDS slice
// (row stride 136 halves to spread banks). K order: k<64 -> s2 = agg+h
// (weight rows 64+k); k>=64 -> s1 = deg*h (weight rows k-64).
// A[m=lane&15][k=quad*8+j]; B[n=lane&15][k=quad*8+j]; D col=lane&15,
// row=quad*4+reg (verified gfx950 layouts).
#define SROW 136

__global__ __launch_bounds__(256, 4) void k_mv_mfma(
    const __half* __restrict__ agg16, const __half* __restrict__ hin16,
    const __half* __restrict__ base16, const float* __restrict__ degf,
    const float* __restrict__ Wmh, __half* __restrict__ hout16) {
    __shared__ __align__(16) _Float16 S[4][16 * SROW];
    int lane = threadIdx.x & 63, wid = threadIdx.x >> 6;
    int n = lane & 15, quad = lane >> 4;
    // B fragments (16 half8 = 64 VGPRs), loaded once
    half8 bfr[4][4];
#pragma unroll
    for (int kk = 0; kk < 4; kk++)
#pragma unroll
        for (int nn = 0; nn < 4; nn++) {
            half8 tmp;
#pragma unroll
            for (int j = 0; j < 8; j++) {
                int kp = kk * 32 + quad * 8 + j;
                int krow = (kp < 64) ? (64 + kp) : (kp - 64);
                tmp[j] = (_Float16)Wmh[krow * FDIM + nn * 16 + n];
            }
            bfr[kk][nn] = tmp;
        }
    int t = blockIdx.x * 4 + wid;
    if (t >= NT) return;
    int tb = t * 16;
    // stage S
    {
        int m = lane >> 2, c = lane & 3;
        int node = tb + m;
        const uint4* ag4 = (const uint4*)agg16;
        const uint4* hh4 = (const uint4*)hin16;
        uint4 agA = ag4[(size_t)node * 8 + c * 2];
        uint4 agB = ag4[(size_t)node * 8 + c * 2 + 1];
        uint4 hA  = hh4[(size_t)node * 8 + c * 2];
        uint4 hB  = hh4[(size_t)node * 8 + c * 2 + 1];
        __half dh = __float2half(degf[node]);
        __half2 dh2 = __halves2half2(dh, dh);
        uint4 s2A, s2B, s1A, s1B;
        s2A.x = hadd2u(agA.x, hA.x); s2A.y = hadd2u(agA.y, hA.y);
        s2A.z = hadd2u(agA.z, hA.z); s2A.w = hadd2u(agA.w, hA.w);
        s2B.x = hadd2u(agB.x, hB.x); s2B.y = hadd2u(agB.y, hB.y);
        s2B.z = hadd2u(agB.z, hB.z); s2B.w = hadd2u(agB.w, hB.w);
        s1A.x = hmul2u(hA.x, dh2); s1A.y = hmul2u(hA.y, dh2);
        s1A.z = hmul2u(hA.z, dh2); s1A.w = hmul2u(hA.w, dh2);
        s1B.x = hmul2u(hB.x, dh2); s1B.y = hmul2u(hB.y, dh2);
        s1B.z = hmul2u(hB.z, dh2); s1B.w = hmul2u(hB.w, dh2);
        uint4* Sw = (uint4*)(&S[wid][m * SROW]);
        Sw[c * 2]     = s2A;
        Sw[c * 2 + 1] = s2B;
        Sw[8 + c * 2]     = s1A;
        Sw[8 + c * 2 + 1] = s1B;
    }
    // C init from base16
    float4v acc[4];
#pragma unroll
    for (int nn = 0; nn < 4; nn++)
#pragma unroll
        for (int r = 0; r < 4; r++)
            acc[nn][r] = __half2float(base16[(size_t)(tb + quad * 4 + r) * FDIM + nn * 16 + n]);
    // MFMA
    const _Float16* Sr = S[wid];
#pragma unroll
    for (int kk = 0; kk < 4; kk++) {
        half8 a = *(const half8*)(Sr + (lane & 15) * SROW + kk * 32 + quad * 8);
#pragma unroll
        for (int nn = 0; nn < 4; nn++)
            acc[nn] = __builtin_amdgcn_mfma_f32_16x16x32_f16(a, bfr[kk][nn], acc[nn], 0, 0, 0);
    }
    // epilogue: relu -> fp16 store
#pragma unroll
    for (int nn = 0; nn < 4; nn++)
#pragma unroll
        for (int r = 0; r < 4; r++)
            hout16[(size_t)(tb + quad * 4 + r) * FDIM + nn * 16 + n] =
                __float2half(fmaxf(acc[nn][r], 0.f));
}

__global__ __launch_bounds__(256, 4) void k_out_mv_mfma(
    const __half* __restrict__ agg16, const __half* __restrict__ hin16,
    const __half* __restrict__ obase16, const float* __restrict__ degf,
    const float* __restrict__ Wom, const float* __restrict__ Wout,
    float* __restrict__ sc) {
    __shared__ __align__(16) _Float16 S[4][16 * SROW];
    int lane = threadIdx.x & 63, wid = threadIdx.x >> 6;
    int n = lane & 15, quad = lane >> 4;
    half8 bfr[4][4];
#pragma unroll
    for (int kk = 0; kk < 4; kk++)
#pragma unroll
        for (int nn = 0; nn < 4; nn++) {
            half8 tmp;
#pragma unroll
            for (int j = 0; j < 8; j++) {
                int kp = kk * 32 + quad * 8 + j;
                int krow = (kp < 64) ? (64 + kp) : (kp - 64);
                tmp[j] = (_Float16)Wom[krow * FDIM + nn * 16 + n];
            }
            bfr[kk][nn] = tmp;
        }
    float wo0 = Wout[n], wo1 = Wout[16 + n], wo2 = Wout[32 + n], wo3 = Wout[48 + n];
    int t = blockIdx.x * 4 + wid;
    if (t >= NT) return;
    int tb = t * 16;
    {
        int m = lane >> 2, c = lane & 3;
        int node = tb + m;
        const uint4* ag4 = (const uint4*)agg16;
        const uint4* hh4 = (const uint4*)hin16;
        uint4 agA = ag4[(size_t)node * 8 + c * 2];
        uint4 agB = ag4[(size_t)node * 8 + c * 2 + 1];
        uint4 hA  = hh4[(size_t)node * 8 + c * 2];
        uint4 hB  = hh4[(size_t)node * 8 + c * 2 + 1];
        __half dh = __float2half(degf[node]);
        __half2 dh2 = __halves2half2(dh, dh);
        uint4 s2A, s2B, s1A, s1B;
        s2A.x = hadd2u(agA.x, hA.x); s2A.y = hadd2u(agA.y, hA.y);
        s2A.z = hadd2u(agA.z, hA.z); s2A.w = hadd2u(agA.w, hA.w);
        s2B.x = hadd2u(agB.x, hB.x); s2B.y = hadd2u(agB.y, hB.y);
        s2B.z = hadd2u(agB.z, hB.z); s2B.w = hadd2u(agB.w, hB.w);
        s1A.x = hmul2u(hA.x, dh2); s1A.y = hmul2u(hA.y, dh2);
        s1A.z = hmul2u(hA.z, dh2); s1A.w = hmul2u(hA.w, dh2);
        s1B.x = hmul2u(hB.x, dh2); s1B.y = hmul2u(hB.y, dh2);
        s1B.z = hmul2u(hB.z, dh2); s1B.w = hmul2u(hB.w, dh2);
        uint4* Sw = (uint4*)(&S[wid][m * SROW]);
        Sw[c * 2]     = s2A;
        Sw[c * 2 + 1] = s2B;
        Sw[8 + c * 2]     = s1A;
        Sw[8 + c * 2 + 1] = s1B;
    }
    float4v acc[4];
#pragma unroll
    for (int nn = 0; nn < 4; nn++)
#pragma unroll
        for (int r = 0; r < 4; r++)
            acc[nn][r] = __half2float(obase16[(size_t)(tb + quad * 4 + r) * FDIM + nn * 16 + n]);
    const _Float16* Sr = S[wid];
#pragma unroll
    for (int kk = 0; kk < 4; kk++) {
        half8 a = *(const half8*)(Sr + (lane & 15) * SROW + kk * 32 + quad * 8);
#pragma unroll
        for (int nn = 0; nn < 4; nn++)
            acc[nn] = __builtin_amdgcn_mfma_f32_16x16x32_f16(a, bfr[kk][nn], acc[nn], 0, 0, 0);
    }
    // sc[node] = sum_out relu(acc)*Wout
#pragma unroll
    for (int r = 0; r < 4; r++) {
        float s = fmaxf(acc[0][r], 0.f) * wo0 + fmaxf(acc[1][r], 0.f) * wo1
                + fmaxf(acc[2][r], 0.f) * wo2 + fmaxf(acc[3][r], 0.f) * wo3;
        s += __shfl_xor(s, 1, 64);
        s += __shfl_xor(s, 2, 64);
        s += __shfl_xor(s, 4, 64);
        s += __shfl_xor(s, 8, 64);
        if (n == 0) sc[tb + quad * 4 + r] = s;
    }
}

// obase = (aggX + x) @ Wom[128:192] + bom   (K=64, 8 MFMAs)
#define SROW2 72
__global__ __launch_bounds__(256, 4) void k_obase_mfma(
    const __half* __restrict__ aggX16, const __half* __restrict__ x16,
    const float* __restrict__ Wom, const float* __restrict__ bom,
    __half* __restrict__ obase16) {
    __shared__ __align__(16) _Float16 S[4][16 * SROW2];
    int lane = threadIdx.x & 63, wid = threadIdx.x >> 6;
    int n = lane & 15, quad = lane >> 4;
    half8 bfr[2][4];
#pragma unroll
    for (int kk = 0; kk < 2; kk++)
#pragma unroll
        for (int nn = 0; nn < 4; nn++) {
            half8 tmp;
#pragma unroll
            for (int j = 0; j < 8; j++) {
                int kp = kk * 32 + quad * 8 + j;
                tmp[j] = (_Float16)Wom[(128 + kp) * FDIM + nn * 16 + n];
            }
            bfr[kk][nn] = tmp;
        }
    float bom_n[4];
#pragma unroll
    for (int nn = 0; nn < 4; nn++) bom_n[nn] = bom[nn * 16 + n];
    int t = blockIdx.x * 4 + wid;
    if (t >= NT) return;
    int tb = t * 16;
    {
        int m = lane >> 2, c = lane & 3;
        int node = tb + m;
        const uint4* ag4 = (const uint4*)aggX16;
        const uint4* xx4 = (const uint4*)x16;
        uint4 agA = ag4[(size_t)node * 8 + c * 2];
        uint4 agB = ag4[(size_t)node * 8 + c * 2 + 1];
        uint4 xA  = xx4[(size_t)node * 8 + c * 2];
        uint4 xB  = xx4[(size_t)node * 8 + c * 2 + 1];
        uint4 sA, sB;
        sA.x = hadd2u(agA.x, xA.x); sA.y = hadd2u(agA.y, xA.y);
        sA.z = hadd2u(agA.z, xA.z); sA.w = hadd2u(agA.w, xA.w);
        sB.x = hadd2u(agB.x, xB.x); sB.y = hadd2u(agB.y, xB.y);
        sB.z = hadd2u(agB.z, xB.z); sB.w = hadd2u(agB.w, xB.w);
        uint4* Sw = (uint4*)(&S[wid][m * SROW2]);
        Sw[c * 2]     = sA;
        Sw[c * 2 + 1] = sB;
    }
    float4v acc[4];
#pragma unroll
    for (int nn = 0; nn < 4; nn++)
#pragma unroll
        for (int r = 0; r < 4; r++) acc[nn][r] = bom_n[nn];
    const _Float16* Sr = S[wid];
#pragma unroll
    for (int kk = 0; kk < 2; kk++) {
        half8 a = *(const half8*)(Sr + (lane & 15) * SROW2 + kk * 32 + quad * 8);
#pragma unroll
        for (int nn = 0; nn < 4; nn++)
            acc[nn] = __builtin_amdgcn_mfma_f32_16x16x32_f16(a, bfr[kk][nn], acc[nn], 0, 0, 0);
    }
#pragma unroll
    for (int nn = 0; nn < 4; nn++)
#pragma unroll
        for (int r = 0; r < 4; r++)
            obase16[(size_t)(tb + quad * 4 + r) * FDIM + nn * 16 + n] =
                __float2half(acc[nn][r]);
}

// out[g] = sum of sc over graph-g nodes + b_out
__global__ void k_pool(const float* __restrict__ sc, const int* __restrict__ batch,
                       const float* __restrict__ b_out, float* __restrict__ out) {
    __shared__ float red[4];
    int g = blockIdx.x, t = threadIdx.x;
    int lo = 0, hi = N_NODES;
    while (lo < hi) { int mid = (lo + hi) >> 1; if (batch[mid] < g) lo = mid + 1; else hi = mid; }
    int lo2 = lo, hi2 = N_NODES;
    while (lo2 < hi2) { int mid = (lo2 + hi2) >> 1; if (batch[mid] < g + 1) lo2 = mid + 1; else hi2 = mid; }
    float s = 0.f;
    for (int i = lo + t; i < lo2; i += 256) s += sc[i];
#pragma unroll
    for (int off = 32; off > 0; off >>= 1) s += __shfl_down(s, off, 64);
    int lane = t & 63, wid = t >> 6;
    if (lane == 0) red[wid] = s;
    __syncthreads();
    if (t == 0) out[g] = red[0] + red[1] + red[2] + red[3] + b_out[0];
}

// ---------------- launcher ----------------

extern "C" void kernel_launch(void* const* d_in, const int* in_sizes, int n_in,
                              void* d_out, int out_size, void* d_ws, size_t ws_size,
                              hipStream_t stream) {
    const float* x         = (const float*)d_in[0];
    const float* edge_attr = (const float*)d_in[1];
    const float* Wnh       = (const float*)d_in[2];
    const float* bnh       = (const float*)d_in[3];
    const float* Wmh       = (const float*)d_in[4];
    const float* bmh       = (const float*)d_in[5];
    const float* Wom       = (const float*)d_in[6];
    const float* bom       = (const float*)d_in[7];
    const float* Wout      = (const float*)d_in[8];
    const float* bout      = (const float*)d_in[9];
    const int*   eidx      = (const int*)d_in[10];
    const int*   batch     = (const int*)d_in[11];
    const int*   srcI = eidx;
    const int*   dstI = eidx + N_EDGES;
    float* out = (float*)d_out;
    (void)in_sizes; (void)n_in; (void)out_size;

    char* w = (char*)d_ws;
    size_t off = 0;
    auto take = [&](size_t b) -> void* {
        void* p = w + off;
        off = (off + b + 255) & ~(size_t)255;
        return p;
    };
    float*  ea     = (float*)take((size_t)N_NODES * EDIM * 4);
    int*    cnt    = (int*)take((size_t)N_NODES * 4);
    int*    rowp   = (int*)take((size_t)(N_NODES + 1) * 4);
    int*    cur    = (int*)take((size_t)N_NODES * 4);
    float*  degf   = (float*)take((size_t)N_NODES * 4);
    int*    col    = (int*)take((size_t)N_EDGES * 4);
    int*    eperm  = (int*)take((size_t)N_EDGES * 4);
    float*  sc     = (float*)take((size_t)N_NODES * 4);
    int*    blks   = (int*)take(256 * 4);
    int*    boff   = (int*)take(256 * 4);
    __half* x16    = (__half*)take((size_t)N_NODES * FDIM * 2);
    __half* hA16   = (__half*)take((size_t)N_NODES * FDIM * 2);
    __half* hB16   = (__half*)take((size_t)N_NODES * FDIM * 2);
    __half* agg16  = (__half*)take((size_t)N_NODES * FDIM * 2);
    __half* base16 = (__half*)take((size_t)N_NODES * FDIM * 2);
    __half* obase16= (__half*)take((size_t)N_NODES * FDIM * 2);
    (void)ws_size;

    const int MVG = (NT + 3) / 4;   // 782 blocks, 1 tile per wave

    hipMemsetAsync(cnt, 0, (size_t)N_NODES * 4, stream);
    k_count<<<(N_EDGES + 255) / 256, 256, 0, stream>>>(dstI, cnt);
    k_cvt_x<<<(N_NODES * FDIM + 255) / 256, 256, 0, stream>>>(x, x16);
    k_blksum<<<NBLK, 256, 0, stream>>>(cnt, blks);
    k_scanblk<<<1, 256, 0, stream>>>(blks, boff, rowp);
    k_rowp<<<NBLK, 256, 0, stream>>>(cnt, boff, rowp, cur, degf);
    k_fill<<<(N_EDGES + 255) / 256, 256, 0, stream>>>(srcI, dstI, cur, col, eperm);

    k_gather<<<2048, 256, 0, stream>>>(x16, rowp, col, agg16);          // aggX
    k_obase_mfma<<<MVG, 256, 0, stream>>>(agg16, x16, Wom, bom, obase16);
    k_ea_agg<<<2048, 256, 0, stream>>>(edge_attr, rowp, eperm, ea);
    k_h0base<<<2048, 256, 0, stream>>>(x, ea, Wnh, bnh, Wmh, bmh, hA16, base16);

    k_gather<<<2048, 256, 0, stream>>>(hA16, rowp, col, agg16);
    k_mv_mfma<<<MVG, 256, 0, stream>>>(agg16, hA16, base16, degf, Wmh, hB16);

    k_gather<<<2048, 256, 0, stream>>>(hB16, rowp, col, agg16);
    k_mv_mfma<<<MVG, 256, 0, stream>>>(agg16, hB16, base16, degf, Wmh, hA16);

    k_gather<<<2048, 256, 0, stream>>>(hA16, rowp, col, agg16);
    k_mv_mfma<<<MVG, 256, 0, stream>>>(agg16, hA16, base16, degf, Wmh, hB16);

    k_gather<<<2048, 256, 0, stream>>>(hB16, rowp, col, agg16);
    k_out_mv_mfma<<<MVG, 256, 0, stream>>>(agg16, hB16, obase16, degf, Wom, Wout, sc);
    k_pool<<<NGRAPH, 256, 0, stream>>>(sc, batch, bout, out);
}